// Round 6
// baseline (329.444 us; speedup 1.0000x reference)
//
#include <hip/hip_runtime.h>
#include <hip/hip_bf16.h>
#include <math.h>

// B=4, T=4096, D=1024, H=4, d=64. Inputs FP32. OUTPUT BUFFER IS FP32
// (deduced R5: tail writes at short-offset 2^24 aliased into the fp32 y
// region producing the bit-stable 436.3 error). Outputs concatenated fp32:
// y [4,4096,1024] at 0, kv_f [4,4,64,64] at 16777216, kc_f [4,4,64] after.
// qkv bf16 scratch lives in d_out's y region (64MB), overwritten by gemm_out
// last. d_ws: cs fp32 17.04MB + yatt bf16 8.39MB = 25.4MB.
#define T_SEQ   4096
#define NB      4
#define NH      4
#define DH      64
#define DM      1024
#define MR      16384
#define NQKV    768
#define CH      64
#define NCH     64
#define SST     4160       // per-chunk state floats: 64*64 + 64
#define BHN     16

typedef __attribute__((ext_vector_type(4))) float          f32x4;
typedef __attribute__((ext_vector_type(8))) short          s16x8;
typedef __attribute__((ext_vector_type(4))) unsigned short u16x4;

__device__ __forceinline__ float bf2f(unsigned short u) {
  union { unsigned int i; float f; } c; c.i = ((unsigned int)u) << 16; return c.f;
}
__device__ __forceinline__ unsigned short f2bf(float f) {
  union { float f; unsigned int i; } c; c.f = f;
  unsigned int i = c.i;
  return (unsigned short)((i + 0x7fffu + ((i >> 16) & 1u)) >> 16);  // RNE
}
__device__ __forceinline__ s16x8 pack8(f32x4 lo, f32x4 hi) {
  s16x8 r;
  r[0] = (short)f2bf(lo.x); r[1] = (short)f2bf(lo.y);
  r[2] = (short)f2bf(lo.z); r[3] = (short)f2bf(lo.w);
  r[4] = (short)f2bf(hi.x); r[5] = (short)f2bf(hi.y);
  r[6] = (short)f2bf(hi.z); r[7] = (short)f2bf(hi.w);
  return r;
}

// ---------------------------------------------------------------------------
// GEMM 1: qkv[16384,768] bf16 = X[16384,1024]fp32 * W^T (fp32->bf16 at LDS
// store). 128x128 tile, 4 waves, 4x4 of 16x16x32 MFMA. XOR-swizzled LDS.
// (R3==R4 bit-identical kc proves this MFMA layout computes the right GEMM.)
// ---------------------------------------------------------------------------
__global__ __launch_bounds__(256, 2) void gemm_qkv_kernel(
    const float* __restrict__ X,
    const float* __restrict__ Wq,
    const float* __restrict__ Wk,
    const float* __restrict__ Wv,
    unsigned short* __restrict__ C)
{
  constexpr int K = DM;
  constexpr int N = NQKV;
  __shared__ unsigned short sA[128 * 32];
  __shared__ unsigned short sB[128 * 32];

  const int tid  = threadIdx.x;
  const int wave = tid >> 6;
  const int lane = tid & 63;
  const int quad = lane >> 4;
  const int l16  = lane & 15;
  const int wm = (wave >> 1) * 64;
  const int wn = (wave & 1) * 64;

  const int row0 = blockIdx.x * 128;
  const int bn   = blockIdx.y;                 // 0..5
  const float* Bt = (bn < 2) ? Wq : (bn < 4) ? Wk : Wv;
  const int brow0 = (bn & 1) * 128;

  const int srow = tid >> 2;
  const int scol = ((tid & 3) ^ (srow & 3)) * 8;
  const float* Ag = X  + (size_t)(row0  + srow) * K + scol;
  const float* Bg = Bt + (size_t)(brow0 + srow) * K + scol;
  unsigned short* sAp = sA + tid * 8;
  unsigned short* sBp = sB + tid * 8;

  const int ra = (quad ^ (l16 & 3)) * 8;

  f32x4 acc[4][4];
  #pragma unroll
  for (int i = 0; i < 4; i++)
    #pragma unroll
    for (int j = 0; j < 4; j++) acc[i][j] = (f32x4){0.f, 0.f, 0.f, 0.f};

  for (int kt = 0; kt < K; kt += 32) {
    const f32x4 a0l = *(const f32x4*)(Ag + kt);
    const f32x4 a0h = *(const f32x4*)(Ag + kt + 4);
    const f32x4 a1l = *(const f32x4*)(Ag + kt + (size_t)64 * K);
    const f32x4 a1h = *(const f32x4*)(Ag + kt + (size_t)64 * K + 4);
    const f32x4 b0l = *(const f32x4*)(Bg + kt);
    const f32x4 b0h = *(const f32x4*)(Bg + kt + 4);
    const f32x4 b1l = *(const f32x4*)(Bg + kt + (size_t)64 * K);
    const f32x4 b1h = *(const f32x4*)(Bg + kt + (size_t)64 * K + 4);
    __syncthreads();
    *(s16x8*)sAp          = pack8(a0l, a0h);
    *(s16x8*)(sAp + 2048) = pack8(a1l, a1h);
    *(s16x8*)sBp          = pack8(b0l, b0h);
    *(s16x8*)(sBp + 2048) = pack8(b1l, b1h);
    __syncthreads();
    s16x8 af[4], bw[4];
    #pragma unroll
    for (int i = 0; i < 4; i++)
      af[i] = *(const s16x8*)(sA + (wm + i * 16 + l16) * 32 + ra);
    #pragma unroll
    for (int j = 0; j < 4; j++)
      bw[j] = *(const s16x8*)(sB + (wn + j * 16 + l16) * 32 + ra);
    #pragma unroll
    for (int i = 0; i < 4; i++)
      #pragma unroll
      for (int j = 0; j < 4; j++)
        acc[i][j] = __builtin_amdgcn_mfma_f32_16x16x32_bf16(af[i], bw[j], acc[i][j], 0, 0, 0);
  }

  const int colb = bn * 128 + wn;
  #pragma unroll
  for (int i = 0; i < 4; i++) {
    const int r = row0 + wm + i * 16 + quad * 4;
    #pragma unroll
    for (int j = 0; j < 4; j++) {
      const int cc = colb + j * 16 + l16;
      #pragma unroll
      for (int g = 0; g < 4; g++)
        C[(size_t)(r + g) * N + cc] = f2bf(acc[i][j][g]);
    }
  }
}

// ---------------------------------------------------------------------------
// GEMM 2: Out[16384,1024] FP32 = yatt[16384,256]bf16 * Wo^T (Wo fp32).
// ---------------------------------------------------------------------------
__global__ __launch_bounds__(256, 2) void gemm_out_kernel(
    const unsigned short* __restrict__ Y,
    const float* __restrict__ Wo,
    float* __restrict__ Out)
{
  constexpr int K = 256;
  constexpr int N = DM;
  __shared__ unsigned short sA[128 * 32];
  __shared__ unsigned short sB[128 * 32];

  const int tid  = threadIdx.x;
  const int wave = tid >> 6;
  const int lane = tid & 63;
  const int quad = lane >> 4;
  const int l16  = lane & 15;
  const int wm = (wave >> 1) * 64;
  const int wn = (wave & 1) * 64;

  const int row0  = blockIdx.x * 128;
  const int bcol0 = blockIdx.y * 128;

  const int srow = tid >> 2;
  const int scol = ((tid & 3) ^ (srow & 3)) * 8;
  const unsigned short* Ag = Y  + (size_t)(row0  + srow) * K + scol;
  const float*          Bg = Wo + (size_t)(bcol0 + srow) * K + scol;
  unsigned short* sAp = sA + tid * 8;
  unsigned short* sBp = sB + tid * 8;

  const int ra = (quad ^ (l16 & 3)) * 8;

  f32x4 acc[4][4];
  #pragma unroll
  for (int i = 0; i < 4; i++)
    #pragma unroll
    for (int j = 0; j < 4; j++) acc[i][j] = (f32x4){0.f, 0.f, 0.f, 0.f};

  for (int kt = 0; kt < K; kt += 32) {
    const s16x8 a0 = *(const s16x8*)(Ag + kt);
    const s16x8 a1 = *(const s16x8*)(Ag + kt + (size_t)64 * K);
    const f32x4 b0l = *(const f32x4*)(Bg + kt);
    const f32x4 b0h = *(const f32x4*)(Bg + kt + 4);
    const f32x4 b1l = *(const f32x4*)(Bg + kt + (size_t)64 * K);
    const f32x4 b1h = *(const f32x4*)(Bg + kt + (size_t)64 * K + 4);
    __syncthreads();
    *(s16x8*)sAp          = a0;
    *(s16x8*)(sAp + 2048) = a1;
    *(s16x8*)sBp          = pack8(b0l, b0h);
    *(s16x8*)(sBp + 2048) = pack8(b1l, b1h);
    __syncthreads();
    s16x8 af[4], bw[4];
    #pragma unroll
    for (int i = 0; i < 4; i++)
      af[i] = *(const s16x8*)(sA + (wm + i * 16 + l16) * 32 + ra);
    #pragma unroll
    for (int j = 0; j < 4; j++)
      bw[j] = *(const s16x8*)(sB + (wn + j * 16 + l16) * 32 + ra);
    #pragma unroll
    for (int i = 0; i < 4; i++)
      #pragma unroll
      for (int j = 0; j < 4; j++)
        acc[i][j] = __builtin_amdgcn_mfma_f32_16x16x32_bf16(af[i], bw[j], acc[i][j], 0, 0, 0);
  }

  #pragma unroll
  for (int i = 0; i < 4; i++) {
    const int r = row0 + wm + i * 16 + quad * 4;
    #pragma unroll
    for (int j = 0; j < 4; j++) {
      const int cc = bcol0 + wn + j * 16 + l16;
      #pragma unroll
      for (int g = 0; g < 4; g++)
        Out[(size_t)(r + g) * N + cc] = acc[i][j][g];   // fp32 store
    }
  }
}

// ---------------------------------------------------------------------------
// Pass 1: per-chunk KV = sum_t k outer v (state[dd][j]) and ksum.
// Feature map (elu+1, unit-L2 over d) fused; one wave per t-row.
// ---------------------------------------------------------------------------
__global__ __launch_bounds__(256) void chunk_sums_kernel(
    const unsigned short* __restrict__ qkv,
    float* __restrict__ cs)          // [BHN*NCH][SST]
{
  const int blk = blockIdx.x;        // bh*NCH + c
  const int bh = blk >> 6, c = blk & 63;
  const int b = bh >> 2, h = bh & 3;
  __shared__ float sK[CH * DH];
  __shared__ float sV[CH * DH];
  const int wave = threadIdx.x >> 6, lane = threadIdx.x & 63;
  const size_t rowbase = ((size_t)b * T_SEQ + (size_t)c * CH) * NQKV + h * DH;

  #pragma unroll 4
  for (int tt = 0; tt < 16; tt++) {
    const int t = tt * 4 + wave;
    const unsigned short* r = qkv + rowbase + (size_t)t * NQKV;
    const float kx = bf2f(r[256 + lane]);
    const float vx = bf2f(r[512 + lane]);
    float pk = kx > 0.f ? kx + 1.f : __expf(kx);   // elu(x)+1
    float sk = pk * pk;
    #pragma unroll
    for (int o = 32; o > 0; o >>= 1) sk += __shfl_xor(sk, o, 64);
    sK[t * DH + lane] = pk / (sqrtf(sk) + 1e-6f);
    sV[t * DH + lane] = vx;
  }
  __syncthreads();

  const int dg = threadIdx.x >> 4;
  const int jg = threadIdx.x & 15;
  f32x4 a0 = (f32x4){0,0,0,0}, a1 = a0, a2 = a0, a3 = a0;
  for (int t = 0; t < CH; t++) {
    const f32x4 k4 = ((const f32x4*)sK)[t * 16 + dg];
    const f32x4 v4 = ((const f32x4*)sV)[t * 16 + jg];
    a0 += k4.x * v4; a1 += k4.y * v4; a2 += k4.z * v4; a3 += k4.w * v4;
  }
  float* o = cs + (size_t)blk * SST;
  ((f32x4*)(o + (dg * 4 + 0) * 64))[jg] = a0;
  ((f32x4*)(o + (dg * 4 + 1) * 64))[jg] = a1;
  ((f32x4*)(o + (dg * 4 + 2) * 64))[jg] = a2;
  ((f32x4*)(o + (dg * 4 + 3) * 64))[jg] = a3;
  if (threadIdx.x < 64) {
    float s = 0.f;
    for (int t = 0; t < CH; t++) s += sK[t * DH + threadIdx.x];
    o[4096 + threadIdx.x] = s;
  }
}

// ---------------------------------------------------------------------------
// Pass 2: exclusive prefix scan over chunks, in-place. Emits kv_f, kc_f as
// FP32 to the output tail (float offsets!).
// ---------------------------------------------------------------------------
__global__ __launch_bounds__(256) void scan_kernel(
    float* __restrict__ cs, float* __restrict__ outTail)
{
  const int gid = blockIdx.x * 256 + threadIdx.x;   // BHN*SST threads
  const int bh = gid / SST;
  const int e  = gid - bh * SST;
  float run = 0.f;
  size_t idx = (size_t)bh * NCH * SST + e;
  for (int c = 0; c < NCH; c++, idx += SST) {
    const float v = cs[idx];
    cs[idx] = run;
    run += v;
  }
  if (e < 4096) {          // kv_f[b,h,j,dd] = state[dd][j] (transpose)
    const int dd = e >> 6, j = e & 63;
    outTail[(size_t)bh * 4096 + j * 64 + dd] = run;
  } else {                 // kc_f[b,h,dd]
    const int dd = e - 4096;
    outTail[BHN * 4096 + (size_t)bh * 64 + dd] = run;
  }
}

// ---------------------------------------------------------------------------
// Pass 3: per-chunk outputs. A = tril(Q K^T); num = Q*S0 + A*V;
// den = q.kcum0 + rowsum(tril A) + eps; y_att = num/den -> bf16 [MR][256].
// ---------------------------------------------------------------------------
__global__ __launch_bounds__(256) void chunk_out_kernel(
    const unsigned short* __restrict__ qkv,
    const float* __restrict__ st,
    unsigned short* __restrict__ yatt)
{
  const int blk = blockIdx.x;
  const int bh = blk >> 6;
  const int c  = blk & 63;
  const int b = bh >> 2, h = bh & 3;
  __shared__ float sQ[CH * 64];
  __shared__ float sKp[CH * 68];
  __shared__ float sV[CH * 64];
  __shared__ float sS[64 * 64];
  __shared__ float sKc[64];
  __shared__ unsigned short sA[CH * CH];

  const int wave = threadIdx.x >> 6, lane = threadIdx.x & 63;
  const size_t rowbase = ((size_t)b * T_SEQ + (size_t)c * CH) * NQKV + h * DH;

  #pragma unroll 4
  for (int tt = 0; tt < 16; tt++) {
    const int t = tt * 4 + wave;
    const unsigned short* r = qkv + rowbase + (size_t)t * NQKV;
    const float qx = bf2f(r[lane]);
    const float kx = bf2f(r[256 + lane]);
    const float vx = bf2f(r[512 + lane]);
    float pq = qx > 0.f ? qx + 1.f : __expf(qx);
    float pk = kx > 0.f ? kx + 1.f : __expf(kx);
    float sq = pq * pq, sk = pk * pk;
    #pragma unroll
    for (int o = 32; o > 0; o >>= 1) {
      sq += __shfl_xor(sq, o, 64);
      sk += __shfl_xor(sk, o, 64);
    }
    sQ [t * 64 + lane] = pq / (sqrtf(sq) + 1e-6f);
    sKp[t * 68 + lane] = pk / (sqrtf(sk) + 1e-6f);
    sV [t * 64 + lane] = vx;
  }

  const float* stp = st + (size_t)blk * SST;
  for (int i = threadIdx.x; i < 1024; i += 256)
    ((f32x4*)sS)[i] = ((const f32x4*)stp)[i];
  if (threadIdx.x < 16)
    ((f32x4*)sKc)[threadIdx.x] = ((const f32x4*)(stp + 4096))[threadIdx.x];
  __syncthreads();

  const int t0  = (threadIdx.x >> 4) * 4;
  const int q16 = threadIdx.x & 15;

  // Phase A: scores A[t0+i][q16 + 16u]
  {
    float aa[4][4];
    #pragma unroll
    for (int i = 0; i < 4; i++)
      #pragma unroll
      for (int u = 0; u < 4; u++) aa[i][u] = 0.f;
    for (int dq = 0; dq < 16; dq++) {
      f32x4 q4[4], k4[4];
      #pragma unroll
      for (int i = 0; i < 4; i++) q4[i] = ((const f32x4*)sQ)[(t0 + i) * 16 + dq];
      #pragma unroll
      for (int u = 0; u < 4; u++) k4[u] = *(const f32x4*)(sKp + (q16 + 16 * u) * 68 + dq * 4);
      #pragma unroll
      for (int i = 0; i < 4; i++)
        #pragma unroll
        for (int u = 0; u < 4; u++)
          aa[i][u] += q4[i].x * k4[u].x + q4[i].y * k4[u].y +
                      q4[i].z * k4[u].z + q4[i].w * k4[u].w;
    }
    #pragma unroll
    for (int i = 0; i < 4; i++)
      #pragma unroll
      for (int u = 0; u < 4; u++)
        sA[(t0 + i) * CH + q16 + 16 * u] = f2bf(aa[i][u]);
  }
  __syncthreads();

  // Phase B: outputs rows t0..t0+3, cols jb*4..jb*4+3
  {
    const int jb = q16;
    f32x4 num[4];
    float den[4];
    #pragma unroll
    for (int i = 0; i < 4; i++) { num[i] = (f32x4){0,0,0,0}; den[i] = 1e-6f; }
    for (int dq = 0; dq < 16; dq++) {
      f32x4 q4[4];
      #pragma unroll
      for (int i = 0; i < 4; i++) q4[i] = ((const f32x4*)sQ)[(t0 + i) * 16 + dq];
      const f32x4 kc4 = ((const f32x4*)sKc)[dq];
      const f32x4 s0 = ((const f32x4*)sS)[(dq * 4 + 0) * 16 + jb];
      const f32x4 s1 = ((const f32x4*)sS)[(dq * 4 + 1) * 16 + jb];
      const f32x4 s2 = ((const f32x4*)sS)[(dq * 4 + 2) * 16 + jb];
      const f32x4 s3 = ((const f32x4*)sS)[(dq * 4 + 3) * 16 + jb];
      #pragma unroll
      for (int i = 0; i < 4; i++) {
        num[i] += q4[i].x * s0 + q4[i].y * s1 + q4[i].z * s2 + q4[i].w * s3;
        den[i] += q4[i].x * kc4.x + q4[i].y * kc4.y + q4[i].z * kc4.z + q4[i].w * kc4.w;
      }
    }
    for (int tp = 0; tp < t0 + 4; tp++) {
      const f32x4 v4 = ((const f32x4*)sV)[tp * 16 + jb];
      #pragma unroll
      for (int i = 0; i < 4; i++) {
        if (tp <= t0 + i) {
          const float av = bf2f(sA[(t0 + i) * CH + tp]);
          num[i] += av * v4;
          den[i] += av;
        }
      }
    }
    #pragma unroll
    for (int i = 0; i < 4; i++) {
      const float inv = 1.f / den[i];
      const f32x4 y = num[i] * inv;
      u16x4 o4;
      o4.x = f2bf(y.x); o4.y = f2bf(y.y); o4.z = f2bf(y.z); o4.w = f2bf(y.w);
      const size_t o = ((size_t)b * T_SEQ + (size_t)c * CH + t0 + i) * 256 + h * 64 + jb * 4;
      *(u16x4*)(yatt + o) = o4;
    }
  }
}

// ---------------------------------------------------------------------------
extern "C" void kernel_launch(void* const* d_in, const int* in_sizes, int n_in,
                              void* d_out, int out_size, void* d_ws, size_t ws_size,
                              hipStream_t stream) {
  const float* X  = (const float*)d_in[0];
  const float* Wq = (const float*)d_in[1];
  const float* Wk = (const float*)d_in[2];
  const float* Wv = (const float*)d_in[3];
  const float* Wo = (const float*)d_in[4];
  float* out = (float*)d_out;                        // FP32 output buffer

  // qkv bf16 [16384,768] (25.2MB) parked inside d_out's fp32 y region
  // (64MB); gemm_out overwrites the whole y region afterwards.
  unsigned short* qkvb = (unsigned short*)d_out;
  float* outTail = out + 16777216;                   // kv_f then kc_f (fp32)
  float*          cs   = (float*)d_ws;               // 17.04MB
  unsigned short* yatt = (unsigned short*)((char*)d_ws + 17039360ull);  // 8.39MB

  gemm_qkv_kernel  <<<dim3(128, 6), 256, 0, stream>>>(X, Wq, Wk, Wv, qkvb);
  chunk_sums_kernel<<<BHN * NCH,    256, 0, stream>>>(qkvb, cs);
  scan_kernel      <<<(BHN * SST) / 256, 256, 0, stream>>>(cs, outTail);
  chunk_out_kernel <<<BHN * NCH,    256, 0, stream>>>(qkvb, cs, yatt);
  gemm_out_kernel  <<<dim3(128, 8), 256, 0, stream>>>(yatt, Wo, out);
}